// Round 3
// baseline (153.449 us; speedup 1.0000x reference)
//
#include <hip/hip_runtime.h>

static constexpr int NN  = 4194304;   // N
static constexpr int NB  = 4096;      // blocks; NB * TPB * 4 rows == NN
static constexpr int TPB = 256;

// ---------------------------------------------------------------------------
// R7: single-kernel version. R4-best compute body (direct float4 loads; the
// read path is pinned at ~2.5-3.2 TB/s regardless of mechanism — schedules
// R4-R7 null, nt-loads R5 null, global_load_lds DMA R6 null), plus a
// fence-free fused finalize:
//   - per-block partials written with agent-scope atomic stores (write-through
//     to coherent point; no wbl2/fence — R3's per-block __threadfence was 5x)
//   - s_waitcnt vmcnt(0), then a two-level completion counter (64 groups of 64
//     blocks -> <=64 RMWs per address, no single-address tail serialization)
//   - last block re-reads partials with agent-scope atomic loads (coherent-
//     point reads; immune to stale poison lines in local L1/L2) and finalizes.
// Counters are __device__ globals: zero-init at module load, NOT poisoned by
// the harness (it only poisons d_ws/d_out), self-reset by the finishers each
// launch. No extra dispatch, no spin, no deadlock mode.
// ---------------------------------------------------------------------------

__device__ int g_cnt[65] = {0};   // [0..63] group counters, [64] master

#define ST_AGENT(pp_, v_) \
    __hip_atomic_store((pp_), (v_), __ATOMIC_RELAXED, __HIP_MEMORY_SCOPE_AGENT)
#define LD_AGENT(pp_) \
    __hip_atomic_load((pp_), __ATOMIC_RELAXED, __HIP_MEMORY_SCOPE_AGENT)

__global__ __launch_bounds__(256) void pfl_main(
    const float* __restrict__ pp,   // pred_prices [N]
    const float* __restrict__ pa,   // pred_actions [N,3]
    const float* __restrict__ tp,   // tgt_prices [N]
    const int*   __restrict__ ta,   // tgt_actions [N] (int32)
    float* __restrict__ bsum,       // [3*NB] per-block partials (d_ws)
    float* __restrict__ out)        // scalar result
{
    const int tid = threadIdx.x;
    const int bid = blockIdx.x;
    const int g   = bid * TPB + tid;   // group of 4 rows
    const int i   = g * 4;

    const float4* pp4 = (const float4*)pp;
    const float4* tp4 = (const float4*)tp;
    const float4* pa4 = (const float4*)pa;
    const int4*   ta4 = (const int4*)ta;

    // ---- loads (all issued up front) -----------------------------------
    float4 p  = pp4[g];
    float4 t  = tp4[g];
    int4   a  = ta4[g];
    float4 A0 = pa4[3*g + 0];
    float4 A1 = pa4[3*g + 1];
    float4 A2 = pa4[3*g + 2];
    float tm1 = (i > 0)      ? tp[i - 1] : 0.f;   // L1 hits
    float tnx = (i + 4 < NN) ? tp[i + 4] : 0.f;

    float tv[6] = {tm1, t.x, t.y, t.z, t.w, tnx};
    float pv[4] = {p.x, p.y, p.z, p.w};
    float rows[4][3] = {{A0.x, A0.y, A0.z},
                        {A0.w, A1.x, A1.y},
                        {A1.z, A1.w, A2.x},
                        {A2.y, A2.z, A2.w}};
    int av[4] = {a.x, a.y, a.z, a.w};

    float sq = 0.f, ce = 0.f, pw = 0.f;

    #pragma unroll
    for (int j = 0; j < 4; ++j) {
        const int idx = i + j;
        // MSE
        float d = pv[j] - tv[j + 1];
        sq += d * d;

        // cross-entropy via logsumexp over 3 logits
        float x0 = rows[j][0], x1 = rows[j][1], x2 = rows[j][2];
        float m  = fmaxf(x0, fmaxf(x1, x2));
        float lse = m + __logf(__expf(x0 - m) + __expf(x1 - m) + __expf(x2 - m));
        float tgt = (av[j] == 0) ? x0 : ((av[j] == 1) ? x1 : x2);
        ce += lse - tgt;

        // argmax (first-max, matches jnp.argmax)
        int pidx = 0;
        float best = x0;
        if (x1 > best) { best = x1; pidx = 1; }
        if (x2 > best) { pidx = 2; }

        float profit = 0.f;
        if (pidx == 0)      profit = (idx + 1 < NN) ? (tv[j + 2] - tv[j + 1]) : 0.f;
        else if (pidx == 2) profit = (idx > 0)      ? (tv[j + 1] - tv[j])     : 0.f;

        pw += 1.f / (1.f + __expf(-10.f * profit));
    }

    // ---- block reduction (wave-64 shuffle -> LDS) ----------------------
    #pragma unroll
    for (int off = 32; off > 0; off >>= 1) {
        sq += __shfl_down(sq, off, 64);
        ce += __shfl_down(ce, off, 64);
        pw += __shfl_down(pw, off, 64);
    }

    __shared__ float s_sq[4], s_ce[4], s_pw[4];
    __shared__ int   s_last;
    const int lane = tid & 63;
    const int wid  = tid >> 6;
    if (lane == 0) { s_sq[wid] = sq; s_ce[wid] = ce; s_pw[wid] = pw; }
    __syncthreads();

    // ---- publish partials + completion counting (tid 0 only) -----------
    if (tid == 0) {
        float bsq = s_sq[0] + s_sq[1] + s_sq[2] + s_sq[3];
        float bce = s_ce[0] + s_ce[1] + s_ce[2] + s_ce[3];
        float bpw = s_pw[0] + s_pw[1] + s_pw[2] + s_pw[3];

        // agent-scope atomic stores: write-through to coherent point
        ST_AGENT(&bsum[bid],          bsq);
        ST_AGENT(&bsum[NB + bid],     bce);
        ST_AGENT(&bsum[2 * NB + bid], bpw);
        // ensure the stores are performed before we are counted done
        asm volatile("s_waitcnt vmcnt(0)" ::: "memory");

        int last = 0;
        const int grp  = bid >> 6;            // 64 contiguous-bid groups of 64
        const int oldg = atomicAdd(&g_cnt[grp], 1);
        if (oldg == 63) {                     // group finisher
            ST_AGENT(&g_cnt[grp], 0);         // self-reset for next launch
            const int oldm = atomicAdd(&g_cnt[64], 1);
            if (oldm == 63) {                 // global last block
                ST_AGENT(&g_cnt[64], 0);      // self-reset master
                last = 1;
            }
        }
        s_last = last;
    }
    __syncthreads();

    // ---- fused finalize: only the last block executes ------------------
    if (s_last) {
        // 4096 floats per array; thread t reads elements [16t, 16t+16).
        // Agent-scope atomic loads -> coherent-point reads (no stale L1/L2).
        double fsq = 0.0, fce = 0.0, fpw = 0.0;
        const int base = tid * 16;
        #pragma unroll 4
        for (int k = 0; k < 16; ++k) {
            fsq += (double)LD_AGENT(&bsum[base + k]);
            fce += (double)LD_AGENT(&bsum[NB + base + k]);
            fpw += (double)LD_AGENT(&bsum[2 * NB + base + k]);
        }

        #pragma unroll
        for (int off = 32; off > 0; off >>= 1) {
            fsq += __shfl_down(fsq, off, 64);
            fce += __shfl_down(fce, off, 64);
            fpw += __shfl_down(fpw, off, 64);
        }

        __shared__ double d_sq[4], d_ce[4], d_pw[4];
        if (lane == 0) { d_sq[wid] = fsq; d_ce[wid] = fce; d_pw[wid] = fpw; }
        __syncthreads();

        if (tid == 0) {
            double tsq = d_sq[0] + d_sq[1] + d_sq[2] + d_sq[3];
            double tce = d_ce[0] + d_ce[1] + d_ce[2] + d_ce[3];
            double tpw = d_pw[0] + d_pw[1] + d_pw[2] + d_pw[3];
            const double inv = 1.0 / (double)NN;
            out[0] = (float)(0.7 * (tce * inv) * (tpw * inv) + 0.3 * (tsq * inv));
        }
    }
}

extern "C" void kernel_launch(void* const* d_in, const int* in_sizes, int n_in,
                              void* d_out, int out_size, void* d_ws, size_t ws_size,
                              hipStream_t stream) {
    const float* pp = (const float*)d_in[0];   // pred_prices
    const float* pa = (const float*)d_in[1];   // pred_actions [N,3]
    const float* tp = (const float*)d_in[2];   // tgt_prices
    const int*   ta = (const int*)d_in[3];     // tgt_actions (int32)
    // d_in[4] (prices) unused by reference.

    float* bsum = (float*)d_ws;                // 3*NB floats = 48 KB

    pfl_main<<<NB, TPB, 0, stream>>>(pp, pa, tp, ta, bsum, (float*)d_out);
}

// Round 4
// 136.306 us; speedup vs baseline: 1.1258x; 1.1258x over previous
//
#include <hip/hip_runtime.h>

static constexpr int NN  = 4194304;   // N
static constexpr int NB  = 4096;      // blocks; NB * TPB * 4 rows == NN
static constexpr int TPB = 256;

// ---------------------------------------------------------------------------
// R8: exact revert to the R4-best two-kernel structure (132.4-134 us).
//
// Session evidence, now counter-backed (R7 finally surfaced pfl_main in the
// rocprof top-5):
//   - pfl_main is LATENCY-bound, not BW/compute-bound: 13% HBM, 16% VALU,
//     0 bank conflicts, FETCH_SIZE 48.6 MB (L3 supplies half of the 96 MB
//     logical reads). Matches the per-CU L1 outstanding-miss (MSHR) model:
//     ~32 lines x 128 B / ~300 ns x 256 CU ~= 2.5-3 TB/s logical read.
//   - All read mechanisms probed: schedules (prev R4-R7) null, nontemporal
//     loads (R5) null, global_load_lds DMA (R6) null.
//   - Fused single-kernel finalize (R7): +19 us regression (agent-scope
//     store + vmcnt(0) + atomic-chain tail serializes block retirement).
//   - Harness poison fills: 2 x 268 MB @ 6.6 TB/s = 81 us, fixed.
// Budget: 81 (fills) + ~38 (main, latency floor) + ~13 (final+gaps) ~= 132.
// ---------------------------------------------------------------------------
__global__ __launch_bounds__(256) void pfl_main(
    const float* __restrict__ pp,   // pred_prices [N]
    const float* __restrict__ pa,   // pred_actions [N,3]
    const float* __restrict__ tp,   // tgt_prices [N]
    const int*   __restrict__ ta,   // tgt_actions [N] (int32)
    float* __restrict__ bsum)       // [3*NB] per-block partials
{
    const int tid = threadIdx.x;
    const int bid = blockIdx.x;
    const int g   = bid * TPB + tid;   // group of 4 rows
    const int i   = g * 4;

    const float4* pp4 = (const float4*)pp;
    const float4* tp4 = (const float4*)tp;
    const float4* pa4 = (const float4*)pa;
    const int4*   ta4 = (const int4*)ta;

    // ---- loads (all issued up front) -----------------------------------
    float4 p  = pp4[g];
    float4 t  = tp4[g];
    int4   a  = ta4[g];
    float4 A0 = pa4[3*g + 0];
    float4 A1 = pa4[3*g + 1];
    float4 A2 = pa4[3*g + 2];
    float tm1 = (i > 0)      ? tp[i - 1] : 0.f;   // L1 hits
    float tnx = (i + 4 < NN) ? tp[i + 4] : 0.f;

    float tv[6] = {tm1, t.x, t.y, t.z, t.w, tnx};
    float pv[4] = {p.x, p.y, p.z, p.w};
    float rows[4][3] = {{A0.x, A0.y, A0.z},
                        {A0.w, A1.x, A1.y},
                        {A1.z, A1.w, A2.x},
                        {A2.y, A2.z, A2.w}};
    int av[4] = {a.x, a.y, a.z, a.w};

    float sq = 0.f, ce = 0.f, pw = 0.f;

    #pragma unroll
    for (int j = 0; j < 4; ++j) {
        const int idx = i + j;
        // MSE
        float d = pv[j] - tv[j + 1];
        sq += d * d;

        // cross-entropy via logsumexp over 3 logits
        float x0 = rows[j][0], x1 = rows[j][1], x2 = rows[j][2];
        float m  = fmaxf(x0, fmaxf(x1, x2));
        float lse = m + __logf(__expf(x0 - m) + __expf(x1 - m) + __expf(x2 - m));
        float tgt = (av[j] == 0) ? x0 : ((av[j] == 1) ? x1 : x2);
        ce += lse - tgt;

        // argmax (first-max, matches jnp.argmax)
        int pidx = 0;
        float best = x0;
        if (x1 > best) { best = x1; pidx = 1; }
        if (x2 > best) { pidx = 2; }

        float profit = 0.f;
        if (pidx == 0)      profit = (idx + 1 < NN) ? (tv[j + 2] - tv[j + 1]) : 0.f;
        else if (pidx == 2) profit = (idx > 0)      ? (tv[j + 1] - tv[j])     : 0.f;

        pw += 1.f / (1.f + __expf(-10.f * profit));
    }

    // ---- block reduction (wave-64 shuffle -> LDS) ----------------------
    #pragma unroll
    for (int off = 32; off > 0; off >>= 1) {
        sq += __shfl_down(sq, off, 64);
        ce += __shfl_down(ce, off, 64);
        pw += __shfl_down(pw, off, 64);
    }

    __shared__ float s_sq[4], s_ce[4], s_pw[4];
    const int lane = tid & 63;
    const int wid  = tid >> 6;
    if (lane == 0) { s_sq[wid] = sq; s_ce[wid] = ce; s_pw[wid] = pw; }
    __syncthreads();

    if (tid == 0) {
        bsum[bid]          = s_sq[0] + s_sq[1] + s_sq[2] + s_sq[3];
        bsum[NB + bid]     = s_ce[0] + s_ce[1] + s_ce[2] + s_ce[3];
        bsum[2 * NB + bid] = s_pw[0] + s_pw[1] + s_pw[2] + s_pw[3];
    }
}

// ---------------------------------------------------------------------------
// Finalize: 1024 threads, float4 loads — each thread grabs one float4 from
// each of the three partial arrays (4096 floats = 1024 float4 each).
// out = 0.7 * (ce/N) * (pw/N) + 0.3 * (sq/N)
// ---------------------------------------------------------------------------
__global__ __launch_bounds__(1024) void pfl_final(const float* __restrict__ bsum,
                                                  float* __restrict__ out) {
    const int tid = threadIdx.x;
    const float4* b4 = (const float4*)bsum;
    const int Q = NB / 4;               // 1024 float4 per array

    float4 vsq = b4[tid];               // array 0: [0,   Q)
    float4 vce = b4[Q + tid];           // array 1: [Q,  2Q)
    float4 vpw = b4[2 * Q + tid];       // array 2: [2Q, 3Q)

    double sq = (double)vsq.x + vsq.y + vsq.z + vsq.w;
    double ce = (double)vce.x + vce.y + vce.z + vce.w;
    double pw = (double)vpw.x + vpw.y + vpw.z + vpw.w;

    #pragma unroll
    for (int off = 32; off > 0; off >>= 1) {
        sq += __shfl_down(sq, off, 64);
        ce += __shfl_down(ce, off, 64);
        pw += __shfl_down(pw, off, 64);
    }

    __shared__ double s_sq[16], s_ce[16], s_pw[16];
    const int lane = tid & 63;
    const int wid  = tid >> 6;
    if (lane == 0) { s_sq[wid] = sq; s_ce[wid] = ce; s_pw[wid] = pw; }
    __syncthreads();

    if (tid == 0) {
        double tsq = 0.0, tce = 0.0, tpw = 0.0;
        #pragma unroll
        for (int w = 0; w < 16; ++w) { tsq += s_sq[w]; tce += s_ce[w]; tpw += s_pw[w]; }
        const double inv = 1.0 / (double)NN;
        out[0] = (float)(0.7 * (tce * inv) * (tpw * inv) + 0.3 * (tsq * inv));
    }
}

extern "C" void kernel_launch(void* const* d_in, const int* in_sizes, int n_in,
                              void* d_out, int out_size, void* d_ws, size_t ws_size,
                              hipStream_t stream) {
    const float* pp = (const float*)d_in[0];   // pred_prices
    const float* pa = (const float*)d_in[1];   // pred_actions [N,3]
    const float* tp = (const float*)d_in[2];   // tgt_prices
    const int*   ta = (const int*)d_in[3];     // tgt_actions (int32)
    // d_in[4] (prices) unused by reference.

    float* bsum = (float*)d_ws;                // 3*NB floats = 48 KB (written, not RMW)

    pfl_main<<<NB, TPB, 0, stream>>>(pp, pa, tp, ta, bsum);
    pfl_final<<<1, 1024, 0, stream>>>(bsum, (float*)d_out);
}